// Round 1
// 956.628 us; speedup vs baseline: 1.3017x; 1.3017x over previous
//
#include <hip/hip_runtime.h>
#include <hip/hip_bf16.h>
#include <cstdint>

typedef __bf16 bf16;
typedef __attribute__((ext_vector_type(4))) __bf16 bf16x4;
typedef __attribute__((ext_vector_type(8))) __bf16 bf16x8;
typedef __attribute__((ext_vector_type(4))) float f32x4;

#define AS1 __attribute__((address_space(1)))
#define AS3 __attribute__((address_space(3)))

__device__ __forceinline__ unsigned short f2bf(float x) {
    union { __bf16 b; unsigned short u; } c;
    c.b = (__bf16)x;
    return c.u;
}

// async global->LDS, 16B per lane. LDS dest = wave-uniform base + lane*16.
__device__ __forceinline__ void gld_lds16(const void* g, void* lds_wave_base) {
#if __has_builtin(__builtin_amdgcn_global_load_lds)
    __builtin_amdgcn_global_load_lds((AS1 void*)(uintptr_t)g,
                                     (AS3 void*)(uint32_t)(uintptr_t)lds_wave_base,
                                     16u, 0, 0u);
#else
    int lane = threadIdx.x & 63;
    *(uint4*)((char*)lds_wave_base + lane * 16) = *(const uint4*)g;
#endif
}

// ---------------- fp32 -> bf16 elementwise ----------------
__global__ __launch_bounds__(256) void cvt_kernel(const float* __restrict__ in,
                                                  bf16* __restrict__ out) {
    int i = (blockIdx.x * 256 + threadIdx.x) * 4;
    float4 v = *(const float4*)&in[i];
    bf16x4 o;
    o[0] = (__bf16)v.x; o[1] = (__bf16)v.y; o[2] = (__bf16)v.z; o[3] = (__bf16)v.w;
    *(bf16x4*)&out[i] = o;
}

// ---------------- fp32 [k][n] -> bf16 out[n][k] transpose+convert, n = 4096 ----------------
__global__ __launch_bounds__(256) void cvt_transpose_kernel(const float* __restrict__ in,
                                                            unsigned short* __restrict__ out, int n) {
    __shared__ unsigned short tile[64][65];
    int t = threadIdx.x;
    int n0 = blockIdx.x * 64, k0 = blockIdx.y * 64;
#pragma unroll
    for (int i = 0; i < 4; i++) {
        int idx = t + i * 256;
        int r = idx >> 4, cc = (idx & 15) * 4;
        float4 v = *(const float4*)&in[(size_t)(k0 + r) * n + n0 + cc];
        tile[r][cc + 0] = f2bf(v.x); tile[r][cc + 1] = f2bf(v.y);
        tile[r][cc + 2] = f2bf(v.z); tile[r][cc + 3] = f2bf(v.w);
    }
    __syncthreads();
#pragma unroll
    for (int i = 0; i < 4; i++) {
        int idx = t + i * 256;
        int nn = idx >> 4, kc = (idx & 15) * 4;
        ushort4 v;
        v.x = tile[kc + 0][nn]; v.y = tile[kc + 1][nn];
        v.z = tile[kc + 2][nn]; v.w = tile[kc + 3][nn];
        *(ushort4*)&out[(size_t)(n0 + nn) * n + k0 + kc] = v;
    }
}

// ---------------- bf16 transpose: out[n][k] = in[k][n], n = 4096 ----------------
__global__ __launch_bounds__(256) void transpose_bf16_kernel(const unsigned short* __restrict__ in,
                                                             unsigned short* __restrict__ out, int n) {
    __shared__ unsigned short tile[64][65];
    int t = threadIdx.x;
    int n0 = blockIdx.x * 64, k0 = blockIdx.y * 64;
#pragma unroll
    for (int i = 0; i < 4; i++) {
        int idx = t + i * 256;
        int r = idx >> 4, cc = (idx & 15) * 4;
        ushort4 v = *(const ushort4*)&in[(size_t)(k0 + r) * n + n0 + cc];
        tile[r][cc + 0] = v.x; tile[r][cc + 1] = v.y;
        tile[r][cc + 2] = v.z; tile[r][cc + 3] = v.w;
    }
    __syncthreads();
#pragma unroll
    for (int i = 0; i < 4; i++) {
        int idx = t + i * 256;
        int nn = idx >> 4, kc = (idx & 15) * 4;
        ushort4 v;
        v.x = tile[kc + 0][nn]; v.y = tile[kc + 1][nn];
        v.z = tile[kc + 2][nn]; v.w = tile[kc + 3][nn];
        *(ushort4*)&out[(size_t)(n0 + nn) * n + k0 + kc] = v;
    }
}

// ================= 256x256 8-phase GEMM: C[m,n] = sum_k A[m,k]*BT[n,k] + bias[n] =================
// MODE 0: write bf16 C, no residual. MODE 1: write fp32 C, add bf16 residual.
//
// LDS per buffer: A.k0 | A.k1 | B.k0 | B.k1, each a [128 lines][128B] sub-array
// holding 256 rows x 32 k as row-pairs per line, XOR-swizzled: phys_slot = log_slot ^ (line&7).
// Staging (global_load_lds) writes LDS linearly; the swizzle is applied by permuting the
// per-lane GLOBAL source (both-sides involution). ds_read_b128 applies the same XOR -> 2-way
// (free) bank aliasing per quarter-wave.

__device__ __forceinline__ void stage_khalf(const bf16* __restrict__ gb, int ldk, int kcol0,
                                            bf16* dst /*16KB sub-array*/) {
    const int t = threadIdx.x;
    const int wave = t >> 6;
#pragma unroll
    for (int i = 0; i < 2; i++) {
        int idx = i * 512 + t;          // 16B unit index 0..1023
        int line = idx >> 3;
        int slot = (idx & 7) ^ (line & 7);
        int row = line * 2 + (slot >> 2);
        int kc = (slot & 3) * 8;
        gld_lds16(gb + (size_t)row * ldk + kcol0 + kc,
                  dst + (size_t)(i * 512 + wave * 64) * 8);
    }
}

__device__ __forceinline__ bf16x8 frag_ld(const bf16* sub, int r, int lq) {
    int line = r >> 1;
    int slot = (((r & 1) << 2) | lq) ^ (line & 7);
    return *(const bf16x8*)((const char*)sub + line * 128 + slot * 16);
}

template <int MODE>
__global__ __launch_bounds__(512, 2) void gemm256_kernel(
    const bf16* __restrict__ A, const bf16* __restrict__ BT,
    const float* __restrict__ bias, const bf16* __restrict__ resid,
    void* __restrict__ Cout, int M, int N, int K) {
    __shared__ __align__(16) bf16 lds[65536];  // 128 KiB: 2 x (A 32KB + B 32KB)
    const int tid = threadIdx.x;
    const int wave = tid >> 6, lane = tid & 63;
    const int lq = lane >> 4, lm = lane & 15;
    const int wr = wave >> 2, wcq = wave & 3;  // 2M x 4N waves

    // XCD-aware swizzle (gridDim.x multiple of 8); each XCD gets 2 contiguous bm panels
    const int nwg = gridDim.x;
    const int chunk = nwg >> 3;
    const int bid = blockIdx.x;
    const int swz = (bid & 7) * chunk + (bid >> 3);
    const unsigned nbn = (unsigned)(N >> 8);
    const int bm = (int)((unsigned)swz / nbn);
    const int bn = (int)((unsigned)swz % nbn);
    const int row0 = bm << 8, col0 = bn << 8;

    const bf16* Ag = A + (size_t)row0 * K;
    const bf16* Bg = BT + (size_t)col0 * K;
    bf16* buf0 = lds;
    bf16* buf1 = lds + 32768;
    const int nT = K >> 6;

    f32x4 acc[8][4];
#pragma unroll
    for (int i = 0; i < 8; i++)
#pragma unroll
        for (int j = 0; j < 4; j++) acc[i][j] = (f32x4){0.f, 0.f, 0.f, 0.f};

    // ---- prologue: tile0 fully + tile1 k0-halves; drain tile0, leave tile1.k0 in flight ----
    stage_khalf(Ag, K, 0, buf0);             // X.Ak0(0)
    stage_khalf(Bg, K, 0, buf0 + 16384);     // X.Bk0(0)
    stage_khalf(Ag, K, 32, buf0 + 8192);     // X.Ak1(0)
    stage_khalf(Bg, K, 32, buf0 + 24576);    // X.Bk1(0)
    stage_khalf(Ag, K, 64, buf1);            // Y.Ak0(1)
    stage_khalf(Bg, K, 64, buf1 + 16384);    // Y.Bk0(1)
    asm volatile("s_waitcnt vmcnt(4)" ::: "memory");
    __builtin_amdgcn_s_barrier();

    bf16x8 a0[4], a1[4], b0[4];
    const int arow = wr * 128 + lm;   // + mt*16 (+64 for upper half)
    const int brow = wcq * 64 + lm;   // + nt*16

    for (int t = 0; t < nT; ++t) {
        bf16* X = (t & 1) ? buf1 : buf0;
        bf16* Y = (t & 1) ? buf0 : buf1;
        const bf16* XA0 = X;
        const bf16* XA1 = X + 8192;
        const bf16* XB0 = X + 16384;
        const bf16* XB1 = X + 24576;
        const int kc1 = (t + 1) << 6;
        const int kc2 = (t + 2) << 6;

        // ---- P1: A[mt0-3,k0] + B[nt0-3,k0]; stage Y.Ak1(t+1); MFMA quad (mt0-3, k0) ----
#pragma unroll
        for (int i = 0; i < 4; i++) a0[i] = frag_ld(XA0, arow + i * 16, lq);
#pragma unroll
        for (int j = 0; j < 4; j++) b0[j] = frag_ld(XB0, brow + j * 16, lq);
        if (t + 1 < nT) stage_khalf(Ag, K, kc1 + 32, Y + 8192);
        __builtin_amdgcn_s_barrier();
        asm volatile("s_waitcnt lgkmcnt(0)" ::: "memory");
        __builtin_amdgcn_s_setprio(1);
#pragma unroll
        for (int i = 0; i < 4; i++)
#pragma unroll
            for (int j = 0; j < 4; j++)
                acc[i][j] = __builtin_amdgcn_mfma_f32_16x16x32_bf16(a0[i], b0[j], acc[i][j], 0, 0, 0);
        __builtin_amdgcn_s_setprio(0);
        __builtin_amdgcn_s_barrier();

        // ---- P2: A[mt4-7,k0]; stage Y.Bk1(t+1); MFMA quad (mt4-7, k0) ----
#pragma unroll
        for (int i = 0; i < 4; i++) a1[i] = frag_ld(XA0, arow + 64 + i * 16, lq);
        if (t + 1 < nT) stage_khalf(Bg, K, kc1 + 32, Y + 24576);
        __builtin_amdgcn_s_barrier();
        asm volatile("s_waitcnt lgkmcnt(0)" ::: "memory");
        __builtin_amdgcn_s_setprio(1);
#pragma unroll
        for (int i = 0; i < 4; i++)
#pragma unroll
            for (int j = 0; j < 4; j++)
                acc[4 + i][j] = __builtin_amdgcn_mfma_f32_16x16x32_bf16(a1[i], b0[j], acc[4 + i][j], 0, 0, 0);
        __builtin_amdgcn_s_setprio(0);
        __builtin_amdgcn_s_barrier();

        // ---- P3: A[mt0-3,k1] + B[nt0-3,k1]; stage X.Ak0(t+2) into just-freed region ----
#pragma unroll
        for (int i = 0; i < 4; i++) a0[i] = frag_ld(XA1, arow + i * 16, lq);
#pragma unroll
        for (int j = 0; j < 4; j++) b0[j] = frag_ld(XB1, brow + j * 16, lq);
        if (t + 2 < nT) stage_khalf(Ag, K, kc2, X);
        __builtin_amdgcn_s_barrier();
        asm volatile("s_waitcnt lgkmcnt(0)" ::: "memory");
        __builtin_amdgcn_s_setprio(1);
#pragma unroll
        for (int i = 0; i < 4; i++)
#pragma unroll
            for (int j = 0; j < 4; j++)
                acc[i][j] = __builtin_amdgcn_mfma_f32_16x16x32_bf16(a0[i], b0[j], acc[i][j], 0, 0, 0);
        __builtin_amdgcn_s_setprio(0);
        __builtin_amdgcn_s_barrier();

        // ---- P4: A[mt4-7,k1]; stage X.Bk0(t+2); counted vmcnt (never 0 until epilogue) ----
#pragma unroll
        for (int i = 0; i < 4; i++) a1[i] = frag_ld(XA1, arow + 64 + i * 16, lq);
        if (t + 2 < nT) stage_khalf(Bg, K, kc2, X + 16384);
        if (t < nT - 2) {
            asm volatile("s_waitcnt vmcnt(4)" ::: "memory");  // drain all of tile t+1
        } else {
            asm volatile("s_waitcnt vmcnt(0)" ::: "memory");  // epilogue drain
        }
        __builtin_amdgcn_s_barrier();
        asm volatile("s_waitcnt lgkmcnt(0)" ::: "memory");
        __builtin_amdgcn_s_setprio(1);
#pragma unroll
        for (int i = 0; i < 4; i++)
#pragma unroll
            for (int j = 0; j < 4; j++)
                acc[4 + i][j] = __builtin_amdgcn_mfma_f32_16x16x32_bf16(a1[i], b0[j], acc[4 + i][j], 0, 0, 0);
        __builtin_amdgcn_s_setprio(0);
        __builtin_amdgcn_s_barrier();
    }

    // epilogue: C/D layout col = lane&15, row = (lane>>4)*4 + reg
#pragma unroll
    for (int nt = 0; nt < 4; nt++) {
        int col = col0 + wcq * 64 + nt * 16 + lm;
        float bv = bias[col];
#pragma unroll
        for (int mt = 0; mt < 8; mt++) {
            int rbase = row0 + wr * 128 + mt * 16 + lq * 4;
#pragma unroll
            for (int r = 0; r < 4; r++) {
                int row = rbase + r;
                float v = acc[mt][nt][r] + bv;
                if (MODE == 0) {
                    ((bf16*)Cout)[(size_t)row * N + col] = (bf16)v;
                } else {
                    v += (float)resid[(size_t)row * N + col];
                    ((float*)Cout)[(size_t)row * N + col] = v;
                }
            }
        }
    }
}

// ---------------- MFMA block-diagonal flash attention + residual ----------------
// grid: (nseg*8, 18). block = (seg, head, 64-row i-tile), 4 waves, 16 Q-rows/wave.
// Q in register A-frags; K tile row-major LDS; V^T tile (pre-transposed global) LDS.
__global__ __launch_bounds__(256, 2) void attn_kernel(
    const bf16* __restrict__ Q, const bf16* __restrict__ K, const bf16* __restrict__ Vt,
    const int* __restrict__ num_rels, const float* __restrict__ X,
    bf16* __restrict__ R1) {
    const float SCALE = 0.044194173824159216f;  // 1/sqrt(512)
    int seg = blockIdx.x >> 3;
    int h = blockIdx.x & 7;
    int S = 0;
    for (int i = 0; i < seg; i++) S += num_rels[i];
    int L = num_rels[seg];
    int i0 = blockIdx.y * 64;
    if (i0 >= L) return;

    __shared__ __align__(16) bf16 Ks[32][520];    // K tile, +8 pad -> conflict-free frags
    __shared__ __align__(16) bf16 Vs[512][40];    // V^T tile, +8 pad
    __shared__ __align__(16) bf16 Ps[4][16][40];  // per-wave P tile (C-layout -> A-layout)

    const int t = threadIdx.x;
    const int wave = t >> 6, lane = t & 63;
    const int lq = lane >> 4, lm = lane & 15;

    // Q rows for this wave, held as 16 A-fragments (row = lm, k-chunk c)
    const int qrow = i0 + wave * 16 + lm;
    const bool qvalid = qrow < L;
    bf16x8 aq[16];
    {
        const bf16* qb = Q + (size_t)(S + qrow) * 4096 + h * 512 + lq * 8;
#pragma unroll
        for (int c = 0; c < 16; c++) {
            bf16x8 v = {};
            if (qvalid) v = *(const bf16x8*)(qb + c * 32);
            aq[c] = v;
        }
    }

    f32x4 accO[32];
#pragma unroll
    for (int i = 0; i < 32; i++) accO[i] = (f32x4){0.f, 0.f, 0.f, 0.f};
    float m_r[4], l_r[4];
#pragma unroll
    for (int r = 0; r < 4; r++) { m_r[r] = -1e30f; l_r[r] = 0.f; }

    for (int j0 = 0; j0 < L; j0 += 32) {
        // stage K tile [32][512] (coalesced; rows past L hold neighboring data -> masked later)
#pragma unroll
        for (int it = 0; it < 8; it++) {
            int c = t + it * 256;
            int r = c >> 6, cc = (c & 63) * 8;
            *(uint4*)&Ks[r][cc] = *(const uint4*)&K[(size_t)(S + j0 + r) * 4096 + h * 512 + cc];
        }
        // stage V^T tile [512][32]
#pragma unroll
        for (int it = 0; it < 8; it++) {
            int c = t + it * 256;
            int r = c >> 2, cc = (c & 3) * 8;
            *(uint4*)&Vs[r][cc] = *(const uint4*)&Vt[(size_t)(h * 512 + r) * 4096 + S + j0 + cc];
        }
        __syncthreads();

        // S = Q K^T : 2 col-subtiles x 16 k-chunks
        f32x4 accS[2];
        accS[0] = (f32x4){0.f, 0.f, 0.f, 0.f};
        accS[1] = (f32x4){0.f, 0.f, 0.f, 0.f};
#pragma unroll
        for (int ct = 0; ct < 2; ct++)
#pragma unroll
            for (int c = 0; c < 16; c++) {
                bf16x8 bk = *(const bf16x8*)&Ks[ct * 16 + lm][c * 32 + lq * 8];
                accS[ct] = __builtin_amdgcn_mfma_f32_16x16x32_bf16(aq[c], bk, accS[ct], 0, 0, 0);
            }

        // online softmax; row i = lq*4 + r (C-layout), col j = j0 + ct*16 + lm
        bool v0 = (j0 + lm) < L, v1 = (j0 + 16 + lm) < L;
        float p0v[4], p1v[4], alpha[4];
#pragma unroll
        for (int r = 0; r < 4; r++) {
            float s0 = v0 ? accS[0][r] * SCALE : -1e30f;
            float s1 = v1 ? accS[1][r] * SCALE : -1e30f;
            float mx = fmaxf(s0, s1);
#pragma unroll
            for (int o = 1; o < 16; o <<= 1) mx = fmaxf(mx, __shfl_xor(mx, o, 64));
            float mnew = fmaxf(m_r[r], mx);
            alpha[r] = __expf(m_r[r] - mnew);
            float p0 = __expf(s0 - mnew), p1 = __expf(s1 - mnew);
            float sum = p0 + p1;
#pragma unroll
            for (int o = 1; o < 16; o <<= 1) sum += __shfl_xor(sum, o, 64);
            l_r[r] = l_r[r] * alpha[r] + sum;
            m_r[r] = mnew;
            p0v[r] = p0; p1v[r] = p1;
        }
        // write P to per-wave LDS tile (C-layout -> A-layout round trip)
#pragma unroll
        for (int r = 0; r < 4; r++) {
            Ps[wave][lq * 4 + r][lm] = (bf16)p0v[r];
            Ps[wave][lq * 4 + r][16 + lm] = (bf16)p1v[r];
        }
        // rescale O
#pragma unroll
        for (int i = 0; i < 32; i++)
#pragma unroll
            for (int r = 0; r < 4; r++) accO[i][r] *= alpha[r];

        // O += P V : A-frag from Ps (same wave; in-order LDS), B-frags from V^T tile
        bf16x8 ap = *(const bf16x8*)&Ps[wave][lm][lq * 8];
#pragma unroll
        for (int ct2 = 0; ct2 < 32; ct2++) {
            bf16x8 bv = *(const bf16x8*)&Vs[ct2 * 16 + lm][lq * 8];
            accO[ct2] = __builtin_amdgcn_mfma_f32_16x16x32_bf16(ap, bv, accO[ct2], 0, 0, 0);
        }
        __syncthreads();
    }

    // epilogue: row = i0 + wave*16 + lq*4 + r, col = ct2*16 + lm
#pragma unroll
    for (int r = 0; r < 4; r++) {
        int row = i0 + wave * 16 + lq * 4 + r;
        if (row >= L) continue;
        float inv = 1.f / l_r[r];
        size_t base = (size_t)(S + row) * 4096 + h * 512;
#pragma unroll
        for (int ct2 = 0; ct2 < 32; ct2++) {
            int col = ct2 * 16 + lm;
            R1[base + col] = (bf16)(accO[ct2][r] * inv + X[base + col]);
        }
    }
}

extern "C" void kernel_launch(void* const* d_in, const int* in_sizes, int n_in,
                              void* d_out, int out_size, void* d_ws, size_t ws_size,
                              hipStream_t stream) {
    const float* prod = (const float*)d_in[0];
    const int* nr = (const int*)d_in[1];
    const float* Wq = (const float*)d_in[2];
    const float* bq = (const float*)d_in[3];
    const float* Wk = (const float*)d_in[4];
    const float* bk = (const float*)d_in[5];
    const float* Wv = (const float*)d_in[6];
    const float* bv = (const float*)d_in[7];
    const float* Wfc = (const float*)d_in[8];
    const float* bfc = (const float*)d_in[9];
    float* out = (float*)d_out;

    const size_t MATB = (size_t)4096 * 4096 * sizeof(bf16);  // 33.55 MB
    char* ws = (char*)d_ws;
    bf16* Xb = (bf16*)(ws + 0 * MATB);   // bf16 prod_rep; later reused as V^T
    bf16* Qb = (bf16*)(ws + 1 * MATB);   // later reused as res1
    bf16* Kb = (bf16*)(ws + 2 * MATB);
    bf16* Vb = (bf16*)(ws + 3 * MATB);
    bf16* WT = (bf16*)(ws + 4 * MATB);   // reused per weight transpose

    int nseg = in_sizes[1];

    dim3 cb(256), cg(16384);
    dim3 tb(256), tg(64, 64);
    dim3 gb(512), gg(256);               // 256x256 tiles: (4096/256)^2 blocks, 1 per CU

    cvt_kernel<<<cg, cb, 0, stream>>>(prod, Xb);

    cvt_transpose_kernel<<<tg, tb, 0, stream>>>(Wq, (unsigned short*)WT, 4096);
    gemm256_kernel<0><<<gg, gb, 0, stream>>>(Xb, WT, bq, nullptr, Qb, 4096, 4096, 4096);
    cvt_transpose_kernel<<<tg, tb, 0, stream>>>(Wk, (unsigned short*)WT, 4096);
    gemm256_kernel<0><<<gg, gb, 0, stream>>>(Xb, WT, bk, nullptr, Kb, 4096, 4096, 4096);
    cvt_transpose_kernel<<<tg, tb, 0, stream>>>(Wv, (unsigned short*)WT, 4096);
    gemm256_kernel<0><<<gg, gb, 0, stream>>>(Xb, WT, bv, nullptr, Vb, 4096, 4096, 4096);

    // V^T into the freed Xb slot
    transpose_bf16_kernel<<<tg, tb, 0, stream>>>((const unsigned short*)Vb, (unsigned short*)Xb, 4096);

    dim3 ab(256), ag(nseg * 8, 18);  // 18 * 64 >= Lmax = 1120
    attn_kernel<<<ag, ab, 0, stream>>>(Qb, Kb, Xb, nr, prod, Qb);

    cvt_transpose_kernel<<<tg, tb, 0, stream>>>(Wfc, (unsigned short*)WT, 4096);
    gemm256_kernel<1><<<gg, gb, 0, stream>>>(Qb, WT, bfc, Qb, out, 4096, 4096, 4096);
}

// Round 2
// 939.897 us; speedup vs baseline: 1.3249x; 1.0178x over previous
//
#include <hip/hip_runtime.h>
#include <hip/hip_bf16.h>
#include <cstdint>

typedef __bf16 bf16;
typedef __attribute__((ext_vector_type(4))) __bf16 bf16x4;
typedef __attribute__((ext_vector_type(8))) __bf16 bf16x8;
typedef __attribute__((ext_vector_type(4))) float f32x4;

#define AS1 __attribute__((address_space(1)))
#define AS3 __attribute__((address_space(3)))

__device__ __forceinline__ unsigned short f2bf(float x) {
    union { __bf16 b; unsigned short u; } c;
    c.b = (__bf16)x;
    return c.u;
}

// async global->LDS, 16B per lane. LDS dest = wave-uniform base + lane*16.
__device__ __forceinline__ void gld_lds16(const void* g, void* lds_wave_base) {
#if __has_builtin(__builtin_amdgcn_global_load_lds)
    __builtin_amdgcn_global_load_lds((AS1 void*)(uintptr_t)g,
                                     (AS3 void*)(uint32_t)(uintptr_t)lds_wave_base,
                                     16u, 0, 0u);
#else
    int lane = threadIdx.x & 63;
    *(uint4*)((char*)lds_wave_base + lane * 16) = *(const uint4*)g;
#endif
}

// ---------------- fp32 -> bf16 elementwise ----------------
__global__ __launch_bounds__(256) void cvt_kernel(const float* __restrict__ in,
                                                  bf16* __restrict__ out) {
    int i = (blockIdx.x * 256 + threadIdx.x) * 4;
    float4 v = *(const float4*)&in[i];
    bf16x4 o;
    o[0] = (__bf16)v.x; o[1] = (__bf16)v.y; o[2] = (__bf16)v.z; o[3] = (__bf16)v.w;
    *(bf16x4*)&out[i] = o;
}

// ---------------- fp32 [k][n] -> bf16 out[n][k] transpose+convert, n = 4096 ----------------
__global__ __launch_bounds__(256) void cvt_transpose_kernel(const float* __restrict__ in,
                                                            unsigned short* __restrict__ out, int n) {
    __shared__ unsigned short tile[64][65];
    int t = threadIdx.x;
    int n0 = blockIdx.x * 64, k0 = blockIdx.y * 64;
#pragma unroll
    for (int i = 0; i < 4; i++) {
        int idx = t + i * 256;
        int r = idx >> 4, cc = (idx & 15) * 4;
        float4 v = *(const float4*)&in[(size_t)(k0 + r) * n + n0 + cc];
        tile[r][cc + 0] = f2bf(v.x); tile[r][cc + 1] = f2bf(v.y);
        tile[r][cc + 2] = f2bf(v.z); tile[r][cc + 3] = f2bf(v.w);
    }
    __syncthreads();
#pragma unroll
    for (int i = 0; i < 4; i++) {
        int idx = t + i * 256;
        int nn = idx >> 4, kc = (idx & 15) * 4;
        ushort4 v;
        v.x = tile[kc + 0][nn]; v.y = tile[kc + 1][nn];
        v.z = tile[kc + 2][nn]; v.w = tile[kc + 3][nn];
        *(ushort4*)&out[(size_t)(n0 + nn) * n + k0 + kc] = v;
    }
}

// ---------------- bf16 transpose: out[n][k] = in[k][n], n = 4096 ----------------
__global__ __launch_bounds__(256) void transpose_bf16_kernel(const unsigned short* __restrict__ in,
                                                             unsigned short* __restrict__ out, int n) {
    __shared__ unsigned short tile[64][65];
    int t = threadIdx.x;
    int n0 = blockIdx.x * 64, k0 = blockIdx.y * 64;
#pragma unroll
    for (int i = 0; i < 4; i++) {
        int idx = t + i * 256;
        int r = idx >> 4, cc = (idx & 15) * 4;
        ushort4 v = *(const ushort4*)&in[(size_t)(k0 + r) * n + n0 + cc];
        tile[r][cc + 0] = v.x; tile[r][cc + 1] = v.y;
        tile[r][cc + 2] = v.z; tile[r][cc + 3] = v.w;
    }
    __syncthreads();
#pragma unroll
    for (int i = 0; i < 4; i++) {
        int idx = t + i * 256;
        int nn = idx >> 4, kc = (idx & 15) * 4;
        ushort4 v;
        v.x = tile[kc + 0][nn]; v.y = tile[kc + 1][nn];
        v.z = tile[kc + 2][nn]; v.w = tile[kc + 3][nn];
        *(ushort4*)&out[(size_t)(n0 + nn) * n + k0 + kc] = v;
    }
}

// ================= 256x256 pipelined GEMM: C[m,n] = sum_k A[m,k]*BT[n,k] + bias[n] =================
// MODE 0: write bf16 C, no residual. MODE 1: write fp32 C, add bf16 residual.
//
// LDS per buffer: A.k0 | A.k1 | B.k0 | B.k1, each a [128 lines][128B] sub-array
// holding 256 rows x 32 k as row-pairs per line, XOR-swizzled: phys_slot = log_slot ^ (line&7).
// Staging (global_load_lds) writes LDS linearly; the swizzle is applied by permuting the
// per-lane GLOBAL source (both-sides involution). ds_read_b128 applies the same XOR -> 2-way
// (free) bank aliasing per quarter-wave (measured: SQ_LDS_BANK_CONFLICT = 0).
//
// Pipeline invariant: ALL of buffer B(t) is resident before tile t starts (vmcnt(4) at
// t-1 end drains s3,s4 of t-2 [k0(t)] and s1,s2 of t-1 [k1(t)]). So intra-tile phases need
// no RAW barriers; only 2 WAR barriers per tile:
//   P2 barrier: all waves' k0 frag-reads drained -> P3/P4 may stage k0(t+2) over them.
//   P4 barrier: all waves' k1 frag-reads drained (-> t+1 may stage k1(t+2)); vmcnt(4)
//               before it makes B(t+1) fully resident -> post-barrier prefetch of next
//               tile's first fragments hides under P4's MFMA cluster.
// Frag ds_reads are issued one phase AHEAD of their MFMA so the LDS pipe runs concurrently
// with the MFMA pipe (this was the round-1 39%-MfmaUtil bug: reads and MFMA serialized).

__device__ __forceinline__ void stage_khalf(const bf16* __restrict__ gb, int ldk, int kcol0,
                                            bf16* dst /*16KB sub-array*/) {
    const int t = threadIdx.x;
    const int wave = t >> 6;
#pragma unroll
    for (int i = 0; i < 2; i++) {
        int idx = i * 512 + t;          // 16B unit index 0..1023
        int line = idx >> 3;
        int slot = (idx & 7) ^ (line & 7);
        int row = line * 2 + (slot >> 2);
        int kc = (slot & 3) * 8;
        gld_lds16(gb + (size_t)row * ldk + kcol0 + kc,
                  dst + (size_t)(i * 512 + wave * 64) * 8);
    }
}

__device__ __forceinline__ bf16x8 frag_ld(const bf16* sub, int r, int lq) {
    int line = r >> 1;
    int slot = (((r & 1) << 2) | lq) ^ (line & 7);
    return *(const bf16x8*)((const char*)sub + line * 128 + slot * 16);
}

template <int MODE>
__global__ __launch_bounds__(512, 2) void gemm256_kernel(
    const bf16* __restrict__ A, const bf16* __restrict__ BT,
    const float* __restrict__ bias, const bf16* __restrict__ resid,
    void* __restrict__ Cout, int M, int N, int K) {
    __shared__ __align__(16) bf16 lds[65536];  // 128 KiB: 2 x (A 32KB + B 32KB)
    const int tid = threadIdx.x;
    const int wave = tid >> 6, lane = tid & 63;
    const int lq = lane >> 4, lm = lane & 15;
    const int wr = wave >> 2, wcq = wave & 3;  // 2M x 4N waves

    // XCD-aware swizzle (gridDim.x multiple of 8)
    const int nwg = gridDim.x;
    const int chunk = nwg >> 3;
    const int bid = blockIdx.x;
    const int swz = (bid & 7) * chunk + (bid >> 3);
    const unsigned nbn = (unsigned)(N >> 8);
    const int bm = (int)((unsigned)swz / nbn);
    const int bn = (int)((unsigned)swz % nbn);
    const int row0 = bm << 8, col0 = bn << 8;

    const bf16* Ag = A + (size_t)row0 * K;
    const bf16* Bg = BT + (size_t)col0 * K;
    bf16* buf0 = lds;
    bf16* buf1 = lds + 32768;
    const int nT = K >> 6;

    f32x4 acc[8][4];
#pragma unroll
    for (int i = 0; i < 8; i++)
#pragma unroll
        for (int j = 0; j < 4; j++) acc[i][j] = (f32x4){0.f, 0.f, 0.f, 0.f};

    // ---- prologue: tile0 fully + tile1 k0-halves; drain tile0, leave tile1.k0 in flight ----
    stage_khalf(Ag, K, 0, buf0);             // B(0).Ak0
    stage_khalf(Bg, K, 0, buf0 + 16384);     // B(0).Bk0
    stage_khalf(Ag, K, 32, buf0 + 8192);     // B(0).Ak1
    stage_khalf(Bg, K, 32, buf0 + 24576);    // B(0).Bk1
    stage_khalf(Ag, K, 64, buf1);            // B(1).Ak0
    stage_khalf(Bg, K, 64, buf1 + 16384);    // B(1).Bk0
    asm volatile("s_waitcnt vmcnt(4)" ::: "memory");
    __builtin_amdgcn_s_barrier();

    const int arow = wr * 128 + lm;   // + mt*16 (+64 for upper half)
    const int brow = wcq * 64 + lm;   // + nt*16

    // initial frag prefetch: a0,b0 <- B(0).k0 (lgkm wait folded into P1's MFMA deps)
    bf16x8 a0[4], a1[4], b0[4], b1[4];
#pragma unroll
    for (int i = 0; i < 4; i++) a0[i] = frag_ld(buf0, arow + i * 16, lq);
#pragma unroll
    for (int j = 0; j < 4; j++) b0[j] = frag_ld(buf0 + 16384, brow + j * 16, lq);

    for (int t = 0; t < nT; ++t) {
        bf16* X = (t & 1) ? buf1 : buf0;     // B(t)
        bf16* Y = (t & 1) ? buf0 : buf1;     // B(t+1)
        const bf16* XA0 = X;
        const bf16* XA1 = X + 8192;
        const bf16* XB1 = X + 24576;
        const int kc1 = (t + 1) << 6;
        const int kc2 = (t + 2) << 6;

        // ---- P1: prefetch a1 (k0 hi-rows); stage s1 = A.k1(t+1); MFMA a0 x b0 ----
#pragma unroll
        for (int i = 0; i < 4; i++) a1[i] = frag_ld(XA0, arow + 64 + i * 16, lq);
        if (t + 1 < nT) stage_khalf(Ag, K, kc1 + 32, Y + 8192);
        __builtin_amdgcn_s_setprio(1);
#pragma unroll
        for (int i = 0; i < 4; i++)
#pragma unroll
            for (int j = 0; j < 4; j++)
                acc[i][j] = __builtin_amdgcn_mfma_f32_16x16x32_bf16(a0[i], b0[j], acc[i][j], 0, 0, 0);
        __builtin_amdgcn_s_setprio(0);

        // ---- P2: all k0 reads drained -> barrier (k0 regions become stageable);
        //          prefetch a0<-Ak1 lo, b1<-Bk1; stage s2 = B.k1(t+1); MFMA a1 x b0 ----
        asm volatile("s_waitcnt lgkmcnt(0)" ::: "memory");
        __builtin_amdgcn_s_barrier();
#pragma unroll
        for (int i = 0; i < 4; i++) a0[i] = frag_ld(XA1, arow + i * 16, lq);
#pragma unroll
        for (int j = 0; j < 4; j++) b1[j] = frag_ld(XB1, brow + j * 16, lq);
        if (t + 1 < nT) stage_khalf(Bg, K, kc1 + 32, Y + 24576);
        __builtin_amdgcn_s_setprio(1);
#pragma unroll
        for (int i = 0; i < 4; i++)
#pragma unroll
            for (int j = 0; j < 4; j++)
                acc[4 + i][j] = __builtin_amdgcn_mfma_f32_16x16x32_bf16(a1[i], b0[j], acc[4 + i][j], 0, 0, 0);
        __builtin_amdgcn_s_setprio(0);

        // ---- P3: prefetch a1<-Ak1 hi; stage s3 = A.k0(t+2) over freed Ak0; MFMA a0 x b1 ----
#pragma unroll
        for (int i = 0; i < 4; i++) a1[i] = frag_ld(XA1, arow + 64 + i * 16, lq);
        if (t + 2 < nT) stage_khalf(Ag, K, kc2, X);
        __builtin_amdgcn_s_setprio(1);
#pragma unroll
        for (int i = 0; i < 4; i++)
#pragma unroll
            for (int j = 0; j < 4; j++)
                acc[i][j] = __builtin_amdgcn_mfma_f32_16x16x32_bf16(a0[i], b1[j], acc[i][j], 0, 0, 0);
        __builtin_amdgcn_s_setprio(0);

        // ---- P4: k1 reads drained; stage s4 = B.k0(t+2); counted vmcnt -> B(t+1) resident;
        //          barrier; prefetch next tile's a0,b0 from B(t+1); MFMA a1 x b1 ----
        asm volatile("s_waitcnt lgkmcnt(0)" ::: "memory");
        if (t + 2 < nT) stage_khalf(Bg, K, kc2, X + 16384);
        if (t < nT - 2) {
            asm volatile("s_waitcnt vmcnt(4)" ::: "memory");
        } else {
            asm volatile("s_waitcnt vmcnt(0)" ::: "memory");
        }
        __builtin_amdgcn_s_barrier();
        if (t + 1 < nT) {
#pragma unroll
            for (int i = 0; i < 4; i++) a0[i] = frag_ld(Y, arow + i * 16, lq);
#pragma unroll
            for (int j = 0; j < 4; j++) b0[j] = frag_ld(Y + 16384, brow + j * 16, lq);
        }
        __builtin_amdgcn_s_setprio(1);
#pragma unroll
        for (int i = 0; i < 4; i++)
#pragma unroll
            for (int j = 0; j < 4; j++)
                acc[4 + i][j] = __builtin_amdgcn_mfma_f32_16x16x32_bf16(a1[i], b1[j], acc[4 + i][j], 0, 0, 0);
        __builtin_amdgcn_s_setprio(0);
    }

    // epilogue: C/D layout col = lane&15, row = (lane>>4)*4 + reg
#pragma unroll
    for (int nt = 0; nt < 4; nt++) {
        int col = col0 + wcq * 64 + nt * 16 + lm;
        float bv = bias[col];
#pragma unroll
        for (int mt = 0; mt < 8; mt++) {
            int rbase = row0 + wr * 128 + mt * 16 + lq * 4;
#pragma unroll
            for (int r = 0; r < 4; r++) {
                int row = rbase + r;
                float v = acc[mt][nt][r] + bv;
                if (MODE == 0) {
                    ((bf16*)Cout)[(size_t)row * N + col] = (bf16)v;
                } else {
                    v += (float)resid[(size_t)row * N + col];
                    ((float*)Cout)[(size_t)row * N + col] = v;
                }
            }
        }
    }
}

// ---------------- MFMA block-diagonal flash attention + residual ----------------
// grid: (nseg*8, 18). block = (seg, head, 64-row i-tile), 4 waves, 16 Q-rows/wave.
// Q in register A-frags; K tile row-major LDS; V^T tile (pre-transposed global) LDS.
__global__ __launch_bounds__(256, 2) void attn_kernel(
    const bf16* __restrict__ Q, const bf16* __restrict__ K, const bf16* __restrict__ Vt,
    const int* __restrict__ num_rels, const float* __restrict__ X,
    bf16* __restrict__ R1) {
    const float SCALE = 0.044194173824159216f;  // 1/sqrt(512)
    int seg = blockIdx.x >> 3;
    int h = blockIdx.x & 7;
    int S = 0;
    for (int i = 0; i < seg; i++) S += num_rels[i];
    int L = num_rels[seg];
    int i0 = blockIdx.y * 64;
    if (i0 >= L) return;

    __shared__ __align__(16) bf16 Ks[32][520];    // K tile, +8 pad -> conflict-free frags
    __shared__ __align__(16) bf16 Vs[512][40];    // V^T tile, +8 pad
    __shared__ __align__(16) bf16 Ps[4][16][40];  // per-wave P tile (C-layout -> A-layout)

    const int t = threadIdx.x;
    const int wave = t >> 6, lane = t & 63;
    const int lq = lane >> 4, lm = lane & 15;

    // Q rows for this wave, held as 16 A-fragments (row = lm, k-chunk c)
    const int qrow = i0 + wave * 16 + lm;
    const bool qvalid = qrow < L;
    bf16x8 aq[16];
    {
        const bf16* qb = Q + (size_t)(S + qrow) * 4096 + h * 512 + lq * 8;
#pragma unroll
        for (int c = 0; c < 16; c++) {
            bf16x8 v = {};
            if (qvalid) v = *(const bf16x8*)(qb + c * 32);
            aq[c] = v;
        }
    }

    f32x4 accO[32];
#pragma unroll
    for (int i = 0; i < 32; i++) accO[i] = (f32x4){0.f, 0.f, 0.f, 0.f};
    float m_r[4], l_r[4];
#pragma unroll
    for (int r = 0; r < 4; r++) { m_r[r] = -1e30f; l_r[r] = 0.f; }

    for (int j0 = 0; j0 < L; j0 += 32) {
        // stage K tile [32][512] (coalesced; rows past L hold neighboring data -> masked later)
#pragma unroll
        for (int it = 0; it < 8; it++) {
            int c = t + it * 256;
            int r = c >> 6, cc = (c & 63) * 8;
            *(uint4*)&Ks[r][cc] = *(const uint4*)&K[(size_t)(S + j0 + r) * 4096 + h * 512 + cc];
        }
        // stage V^T tile [512][32]
#pragma unroll
        for (int it = 0; it < 8; it++) {
            int c = t + it * 256;
            int r = c >> 2, cc = (c & 3) * 8;
            *(uint4*)&Vs[r][cc] = *(const uint4*)&Vt[(size_t)(h * 512 + r) * 4096 + S + j0 + cc];
        }
        __syncthreads();

        // S = Q K^T : 2 col-subtiles x 16 k-chunks
        f32x4 accS[2];
        accS[0] = (f32x4){0.f, 0.f, 0.f, 0.f};
        accS[1] = (f32x4){0.f, 0.f, 0.f, 0.f};
#pragma unroll
        for (int ct = 0; ct < 2; ct++)
#pragma unroll
            for (int c = 0; c < 16; c++) {
                bf16x8 bk = *(const bf16x8*)&Ks[ct * 16 + lm][c * 32 + lq * 8];
                accS[ct] = __builtin_amdgcn_mfma_f32_16x16x32_bf16(aq[c], bk, accS[ct], 0, 0, 0);
            }

        // online softmax; row i = lq*4 + r (C-layout), col j = j0 + ct*16 + lm
        bool v0 = (j0 + lm) < L, v1 = (j0 + 16 + lm) < L;
        float p0v[4], p1v[4], alpha[4];
#pragma unroll
        for (int r = 0; r < 4; r++) {
            float s0 = v0 ? accS[0][r] * SCALE : -1e30f;
            float s1 = v1 ? accS[1][r] * SCALE : -1e30f;
            float mx = fmaxf(s0, s1);
#pragma unroll
            for (int o = 1; o < 16; o <<= 1) mx = fmaxf(mx, __shfl_xor(mx, o, 64));
            float mnew = fmaxf(m_r[r], mx);
            alpha[r] = __expf(m_r[r] - mnew);
            float p0 = __expf(s0 - mnew), p1 = __expf(s1 - mnew);
            float sum = p0 + p1;
#pragma unroll
            for (int o = 1; o < 16; o <<= 1) sum += __shfl_xor(sum, o, 64);
            l_r[r] = l_r[r] * alpha[r] + sum;
            m_r[r] = mnew;
            p0v[r] = p0; p1v[r] = p1;
        }
        // write P to per-wave LDS tile (C-layout -> A-layout round trip)
#pragma unroll
        for (int r = 0; r < 4; r++) {
            Ps[wave][lq * 4 + r][lm] = (bf16)p0v[r];
            Ps[wave][lq * 4 + r][16 + lm] = (bf16)p1v[r];
        }
        // rescale O
#pragma unroll
        for (int i = 0; i < 32; i++)
#pragma unroll
            for (int r = 0; r < 4; r++) accO[i][r] *= alpha[r];

        // O += P V : A-frag from Ps (same wave; in-order LDS), B-frags from V^T tile
        bf16x8 ap = *(const bf16x8*)&Ps[wave][lm][lq * 8];
#pragma unroll
        for (int ct2 = 0; ct2 < 32; ct2++) {
            bf16x8 bv = *(const bf16x8*)&Vs[ct2 * 16 + lm][lq * 8];
            accO[ct2] = __builtin_amdgcn_mfma_f32_16x16x32_bf16(ap, bv, accO[ct2], 0, 0, 0);
        }
        __syncthreads();
    }

    // epilogue: row = i0 + wave*16 + lq*4 + r, col = ct2*16 + lm
#pragma unroll
    for (int r = 0; r < 4; r++) {
        int row = i0 + wave * 16 + lq * 4 + r;
        if (row >= L) continue;
        float inv = 1.f / l_r[r];
        size_t base = (size_t)(S + row) * 4096 + h * 512;
#pragma unroll
        for (int ct2 = 0; ct2 < 32; ct2++) {
            int col = ct2 * 16 + lm;
            R1[base + col] = (bf16)(accO[ct2][r] * inv + X[base + col]);
        }
    }
}

extern "C" void kernel_launch(void* const* d_in, const int* in_sizes, int n_in,
                              void* d_out, int out_size, void* d_ws, size_t ws_size,
                              hipStream_t stream) {
    const float* prod = (const float*)d_in[0];
    const int* nr = (const int*)d_in[1];
    const float* Wq = (const float*)d_in[2];
    const float* bq = (const float*)d_in[3];
    const float* Wk = (const float*)d_in[4];
    const float* bk = (const float*)d_in[5];
    const float* Wv = (const float*)d_in[6];
    const float* bv = (const float*)d_in[7];
    const float* Wfc = (const float*)d_in[8];
    const float* bfc = (const float*)d_in[9];
    float* out = (float*)d_out;

    const size_t MATB = (size_t)4096 * 4096 * sizeof(bf16);  // 33.55 MB
    char* ws = (char*)d_ws;
    bf16* Xb = (bf16*)(ws + 0 * MATB);   // bf16 prod_rep; later reused as V^T
    bf16* Qb = (bf16*)(ws + 1 * MATB);   // later reused as res1
    bf16* Kb = (bf16*)(ws + 2 * MATB);
    bf16* Vb = (bf16*)(ws + 3 * MATB);
    bf16* WT = (bf16*)(ws + 4 * MATB);   // reused per weight transpose

    int nseg = in_sizes[1];

    dim3 cb(256), cg(16384);
    dim3 tb(256), tg(64, 64);
    dim3 gb(512), gg(256);               // 256x256 tiles: (4096/256)^2 blocks, 1 per CU

    cvt_kernel<<<cg, cb, 0, stream>>>(prod, Xb);

    cvt_transpose_kernel<<<tg, tb, 0, stream>>>(Wq, (unsigned short*)WT, 4096);
    gemm256_kernel<0><<<gg, gb, 0, stream>>>(Xb, WT, bq, nullptr, Qb, 4096, 4096, 4096);
    cvt_transpose_kernel<<<tg, tb, 0, stream>>>(Wk, (unsigned short*)WT, 4096);
    gemm256_kernel<0><<<gg, gb, 0, stream>>>(Xb, WT, bk, nullptr, Kb, 4096, 4096, 4096);
    cvt_transpose_kernel<<<tg, tb, 0, stream>>>(Wv, (unsigned short*)WT, 4096);
    gemm256_kernel<0><<<gg, gb, 0, stream>>>(Xb, WT, bv, nullptr, Vb, 4096, 4096, 4096);

    // V^T into the freed Xb slot
    transpose_bf16_kernel<<<tg, tb, 0, stream>>>((const unsigned short*)Vb, (unsigned short*)Xb, 4096);

    dim3 ab(256), ag(nseg * 8, 18);  // 18 * 64 >= Lmax = 1120
    attn_kernel<<<ag, ab, 0, stream>>>(Qb, Kb, Xb, nr, prod, Qb);

    cvt_transpose_kernel<<<tg, tb, 0, stream>>>(Wfc, (unsigned short*)WT, 4096);
    gemm256_kernel<1><<<gg, gb, 0, stream>>>(Qb, WT, bfc, Qb, out, 4096, 4096, 4096);
}